// Round 11
// baseline (115.875 us; speedup 1.0000x reference)
//
#include <hip/hip_runtime.h>
#include <hip/hip_bf16.h>
#include <stdint.h>

typedef float f32x4 __attribute__((ext_vector_type(4)));
typedef short short8 __attribute__((ext_vector_type(8)));
typedef __bf16 bf16x8 __attribute__((ext_vector_type(8)));

#define D_MODEL 512
#define MAX_LEN 1024
#define M_TOTAL 65536

static __device__ __forceinline__ short f2bf(float f) {
  union { __hip_bfloat16 h; short s; } u;
  u.h = __float2bfloat16(f);
  return u.s;
}

static __device__ __forceinline__ bf16x8 as_bf16x8(short8 s) {
  union { short8 s; bf16x8 b; } u;
  u.s = s;
  return u.b;
}

// async global->LDS, 16B per lane. LDS dest must be wave-uniform base + lane*16.
static __device__ __forceinline__ void gload_lds16(const void* g, void* l) {
  __builtin_amdgcn_global_load_lds(
      (const __attribute__((address_space(1))) uint32_t*)(uintptr_t)g,
      (__attribute__((address_space(3))) uint32_t*)(uint32_t)(uintptr_t)l,
      16, 0, 0);
}

static __device__ __forceinline__ void mfma_bf16(f32x4& c, short8 a, short8 b) {
  asm("v_mfma_f32_16x16x32_bf16 %0, %1, %2, %0" : "+v"(c) : "v"(a), "v"(b));
}

// ---------------- prep: W [1024][512] f32 -> WtopT / WbotT [512][512] bf16 ([n][k]) ----
__global__ __launch_bounds__(256) void prep_w_kernel(const float* __restrict__ W,
                                                     short* __restrict__ WtT,
                                                     short* __restrict__ WbT) {
  __shared__ float tile[64][65];
  const int t = threadIdx.x;
  const int nt = blockIdx.x * 64;   // n tile in [0,512)
  const int kt = blockIdx.y * 64;   // k tile in [0,1024)
  const int c = t & 63;
  const int r0 = t >> 6;
#pragma unroll
  for (int r = r0; r < 64; r += 4)
    tile[r][c] = W[(size_t)(kt + r) * D_MODEL + nt + c];
  __syncthreads();
  short* dst = (kt < D_MODEL) ? WtT : WbT;
  const int kb = kt & (D_MODEL - 1);
#pragma unroll
  for (int n = r0; n < 64; n += 4)
    dst[(size_t)(nt + n) * D_MODEL + kb + c] = f2bf(tile[c][n]);
}

// ---------------- prep: encoding [1024][512] f32 -> bf16 (row-major) -------------------
__global__ __launch_bounds__(256) void prep_enc_kernel(const float* __restrict__ enc,
                                                       short* __restrict__ encb) {
  const int i = (blockIdx.x * 256 + threadIdx.x) * 4;
  float4 v = *reinterpret_cast<const float4*>(enc + i);
  short4 r = make_short4(f2bf(v.x), f2bf(v.y), f2bf(v.z), f2bf(v.w));
  *reinterpret_cast<short4*>(encb + i) = r;
}

// ---------------- GEMM1: encW[1024][512] = enc_bf16 @ WtopT^T (fp32 out) ---------------
__global__ __launch_bounds__(256) void gemm_encw_kernel(const short* __restrict__ A,
                                                        const short* __restrict__ BT,
                                                        float* __restrict__ C) {
  __shared__ short As[128 * 32];
  __shared__ short Bs[128 * 32];
  const int t = threadIdx.x;
  const int lane = t & 63;
  const int wave = t >> 6;
  const int wm = wave >> 1, wn = wave & 1;
  const int m0 = blockIdx.y * 128, n0 = blockIdx.x * 128;
  const int koff = (t & 3) * 8;
  const int rr = t >> 2;
  const int l15 = lane & 15, lk = (lane >> 4) * 8;
  f32x4 acc[4][4] = {};
  for (int kt = 0; kt < D_MODEL; kt += 32) {
    __syncthreads();
    gload_lds16(A + (size_t)(m0 + rr) * D_MODEL + kt + koff, (char*)As + t * 16);
    gload_lds16(A + (size_t)(m0 + 64 + rr) * D_MODEL + kt + koff, (char*)As + 4096 + t * 16);
    gload_lds16(BT + (size_t)(n0 + rr) * D_MODEL + kt + koff, (char*)Bs + t * 16);
    gload_lds16(BT + (size_t)(n0 + 64 + rr) * D_MODEL + kt + koff, (char*)Bs + 4096 + t * 16);
    __syncthreads();
    short8 af[4], bfr[4];
#pragma unroll
    for (int mi = 0; mi < 4; ++mi)
      af[mi] = *reinterpret_cast<const short8*>(&As[(wm * 64 + mi * 16 + l15) * 32 + lk]);
#pragma unroll
    for (int ni = 0; ni < 4; ++ni)
      bfr[ni] = *reinterpret_cast<const short8*>(&Bs[(wn * 64 + ni * 16 + l15) * 32 + lk]);
#pragma unroll
    for (int mi = 0; mi < 4; ++mi)
#pragma unroll
      for (int ni = 0; ni < 4; ++ni)
        mfma_bf16(acc[mi][ni], af[mi], bfr[ni]);
  }
#pragma unroll
  for (int mi = 0; mi < 4; ++mi)
#pragma unroll
    for (int r = 0; r < 4; ++r) {
      const int row = m0 + wm * 64 + mi * 16 + (lane >> 4) * 4 + r;
#pragma unroll
      for (int ni = 0; ni < 4; ++ni) {
        const int col = n0 + wn * 64 + ni * 16 + l15;
        C[(size_t)row * D_MODEL + col] = acc[mi][ni][r];
      }
    }
}

// ---------------- GEMM2: out = latent @ WbotT^T + encW[dfn] + encW[dfa] + b ------------
// m97-template: BM=BN=128, BK=32, 4 waves (2x2), single-buffered LDS, 2 barriers/step,
// BOTH operands staged via global_load_lds (zero staging VALU, zero reg staging):
//   A staged as RAW F32 [128][32] (16KB); cvt f32->bf16 happens in the COMPUTE phase
//   (v_cvt_pk on the VALU pipe, overlapping MFMA). B bf16 [128][32] (8KB).
// 24KB LDS + <=128 VGPR (launch_bounds(256,4)) -> 4 blocks/CU = 4 barrier groups/SIMD
// interleaving their vmcnt(0) drains (the m97/m114 latency-hiding mechanism).
// Swizzles (applied via pre-swizzled GLOBAL source; LDS dest linear — rule #21):
//   A (8 slots/row of 16B): slot s -> s ^ (row&7)      (frag reads 2-way = free)
//   B (4 slots/row of 16B): slot s -> s ^ ((row>>1)&3) (frag reads 2-way = free)
__global__ __launch_bounds__(256, 4) void gemm_main_kernel(
    const float* __restrict__ latent,   // [65536][512] f32
    const short* __restrict__ BT,       // WbotT [512][512] bf16 ([n][k])
    const float* __restrict__ encW,     // [1024][512] f32
    const int* __restrict__ dfn,
    const int* __restrict__ dfa,
    const float* __restrict__ bias,     // [512]
    float* __restrict__ out) {          // [65536][512] f32
  __shared__ alignas(16) float Af[128 * 32];   // 16 KB, rows of 128B = 8x16B slots
  __shared__ alignas(16) short Bs[128 * 32];   // 8 KB,  rows of 64B  = 4x16B slots
  const int t = threadIdx.x;
  const int lane = t & 63;
  const int wave = t >> 6;
  const int wm = wave >> 1, wn = wave & 1;

  // XCD-chunked mapping: xcd = bid&7 owns m-panels [xcd*64, xcd*64+64);
  // 4 n-blocks of each m-panel consecutive -> same-XCD L2 reuse of A.
  const int bid = blockIdx.x;
  const int slot = bid >> 3;
  const int mblk = (bid & 7) * 64 + (slot >> 2);
  const int nblk = slot & 3;
  const int m0 = mblk * 128, n0 = nblk * 128;

  const int l15 = lane & 15;
  const int lsl = lane >> 4;   // k sub-slot 0..3

  // A staging: pass p (0..3): LDS linear byte p*4096 + t*16 = (row p*32 + (t>>3), slot t&7)
  // global col pre-swizzled: f32 col = kt + ((t&7) ^ ((t>>3)&7)) * 4
  const int arow = t >> 3;                       // row within 32-row pass group
  const int acol = ((t & 7) ^ (arow & 7)) * 4;   // swizzled f32 col offset
  const float* aSrc[4];
#pragma unroll
  for (int p = 0; p < 4; ++p)
    aSrc[p] = latent + (size_t)(m0 + p * 32 + arow) * D_MODEL + acol;

  // B staging: pass p (0..1): LDS linear byte p*4096 + t*16 = (row p*64 + (t>>2), slot t&3)
  // global col pre-swizzled: bf16 col = kt + ((t&3) ^ ((t>>3)&3)) * 8
  const int brow = t >> 2;
  const int bcol = ((t & 3) ^ ((t >> 3) & 3)) * 8;
  const short* bSrc[2];
#pragma unroll
  for (int p = 0; p < 2; ++p)
    bSrc[p] = BT + (size_t)(n0 + p * 64 + brow) * D_MODEL + bcol;

  f32x4 acc[4][4] = {};

  for (int kt = 0; kt < D_MODEL; kt += 32) {
    __syncthreads();   // prev compute done reading LDS
    // ---- stage A (f32, 4x) and B (bf16, 2x) via global_load_lds ----
#pragma unroll
    for (int p = 0; p < 4; ++p)
      gload_lds16(aSrc[p] + kt, (char*)Af + p * 4096 + t * 16);
#pragma unroll
    for (int p = 0; p < 2; ++p)
      gload_lds16(bSrc[p] + kt, (char*)Bs + p * 4096 + t * 16);
    __syncthreads();   // vmcnt(0)+barrier: staged tile visible
    // ---- compute: frag reads (swizzled), cvt A in-reg, 16 MFMA ----
    bf16x8 af[4], bfv[4];
#pragma unroll
    for (int mi = 0; mi < 4; ++mi) {
      const int r = wm * 64 + mi * 16 + l15;
      const int s0 = (2 * lsl) ^ (r & 7);
      const int s1 = (2 * lsl + 1) ^ (r & 7);
      f32x4 v0 = *reinterpret_cast<const f32x4*>((const char*)Af + r * 128 + s0 * 16);
      f32x4 v1 = *reinterpret_cast<const f32x4*>((const char*)Af + r * 128 + s1 * 16);
      short8 h;
      h[0] = f2bf(v0[0]); h[1] = f2bf(v0[1]); h[2] = f2bf(v0[2]); h[3] = f2bf(v0[3]);
      h[4] = f2bf(v1[0]); h[5] = f2bf(v1[1]); h[6] = f2bf(v1[2]); h[7] = f2bf(v1[3]);
      af[mi] = as_bf16x8(h);
    }
#pragma unroll
    for (int ni = 0; ni < 4; ++ni) {
      const int r = wn * 64 + ni * 16 + l15;
      const int s = lsl ^ ((r >> 1) & 3);
      bfv[ni] = as_bf16x8(
          *reinterpret_cast<const short8*>((const char*)Bs + r * 64 + s * 16));
    }
#pragma unroll
    for (int mi = 0; mi < 4; ++mi)
#pragma unroll
      for (int ni = 0; ni < 4; ++ni)
        acc[mi][ni] = __builtin_amdgcn_mfma_f32_16x16x32_bf16(
            af[mi], bfv[ni], acc[mi][ni], 0, 0, 0);
  }

  // epilogue: fused gather of encW rows (2 MB, L2/L3-resident) + bias
#pragma unroll
  for (int mi = 0; mi < 4; ++mi) {
#pragma unroll
    for (int r = 0; r < 4; ++r) {
      const int row = m0 + wm * 64 + mi * 16 + lsl * 4 + r;
      const int d1 = dfn[row];
      const int d2 = dfa[row];
      const float* e1 = encW + (size_t)d1 * D_MODEL;
      const float* e2 = encW + (size_t)d2 * D_MODEL;
      const size_t ro = (size_t)row * D_MODEL;
#pragma unroll
      for (int ni = 0; ni < 4; ++ni) {
        const int col = n0 + wn * 64 + ni * 16 + l15;
        out[ro + col] = acc[mi][ni][r] + e1[col] + e2[col] + bias[col];
      }
    }
  }
}

extern "C" void kernel_launch(void* const* d_in, const int* in_sizes, int n_in,
                              void* d_out, int out_size, void* d_ws, size_t ws_size,
                              hipStream_t stream) {
  const int* dfn = (const int*)d_in[0];
  const int* dfa = (const int*)d_in[1];
  const float* latent = (const float*)d_in[2];
  const float* enc = (const float*)d_in[3];
  const float* W = (const float*)d_in[4];
  const float* bias = (const float*)d_in[5];
  float* out = (float*)d_out;

  // workspace layout (4 MB total)
  char* ws = (char*)d_ws;
  short* WtT  = (short*)(ws);                       // 512KB  [512][512] bf16
  short* WbT  = (short*)(ws + 512 * 1024);          // 512KB  [512][512] bf16
  short* encb = (short*)(ws + 1024 * 1024);         // 1MB    [1024][512] bf16
  float* encW = (float*)(ws + 2 * 1024 * 1024);     // 2MB    [1024][512] f32

  hipLaunchKernelGGL(prep_w_kernel, dim3(8, 16), dim3(256), 0, stream, W, WtT, WbT);
  hipLaunchKernelGGL(prep_enc_kernel, dim3(512), dim3(256), 0, stream, enc, encb);
  hipLaunchKernelGGL(gemm_encw_kernel, dim3(4, 8), dim3(256), 0, stream, encb, WtT, encW);
  hipLaunchKernelGGL(gemm_main_kernel, dim3(2048), dim3(256), 0, stream,
                     latent, WbT, encW, dfn, dfa, bias, out);
}